// Round 7
// baseline (426.042 us; speedup 1.0000x reference)
//
#include <hip/hip_runtime.h>
#include <hip/hip_bf16.h>
#include <math.h>

typedef __attribute__((ext_vector_type(8))) short bf16x8;
typedef __attribute__((ext_vector_type(4))) float f32x4;

typedef void __attribute__((address_space(1))) gvoid_t;
typedef void __attribute__((address_space(3))) lvoid_t;

#define KP0   1856          // 29 fields x 64 (26 onehot + 2 multihot + 1 dense/pad)
#define NB    16384
// workspace layout (bytes)
#define OFF_H0   0u          // 16384*1024*2 = 33554432
#define OFF_W0T  33554432u   // 1856*1024*2  = 3801088
#define OFF_W1T  37355520u   // 1024*512*2   = 1048576
#define OFF_FM   38404096u   // 16384*4
#define OFF_NN   38469632u   // 16384*4
#define OFF_XD   38535168u   // 16384*64*2   = 2097152

#define VMCNT(n) asm volatile("s_waitcnt vmcnt(" #n ")" ::: "memory")
#define LGKM0()  asm volatile("s_waitcnt lgkmcnt(0)" ::: "memory")
#define SBAR0()  __builtin_amdgcn_sched_barrier(0)

template<int N> __device__ __forceinline__ void vmw() {
    asm volatile("s_waitcnt vmcnt(%0)" :: "n"(N) : "memory");
}

__device__ __forceinline__ float bf2f(short s) {
    return __uint_as_float(((unsigned)(unsigned short)s) << 16);
}

__device__ __forceinline__ short f2bf(float x) {
    union { __hip_bfloat16 b; short s; } u; u.b = __float2bfloat16(x); return u.s;
}

__device__ __forceinline__ bf16x8 pack8(f32x4 lo, f32x4 hi) {
    bf16x8 r;
    #pragma unroll
    for (int i = 0; i < 4; ++i) { r[i] = f2bf(lo[i]); r[4 + i] = f2bf(hi[i]); }
    return r;
}

__device__ __forceinline__ void load_lds16(const void* g, void* l) {
    __builtin_amdgcn_global_load_lds(
        (gvoid_t*)(uintptr_t)g,
        (lvoid_t*)(unsigned)(uintptr_t)l,
        16, 0, 0);
}

// ==================== prep_mini: W0T/W1T transposes + Xd(dense pad) + NN zero
__device__ __forceinline__ void transpose_tile(const float* __restrict__ W,
                                               __hip_bfloat16* __restrict__ WT,
                                               int K, int N, int KP, int k0, int n0,
                                               float (*tile)[33], int tid) {
    const int tx = tid & 31, ty = tid >> 5;
    #pragma unroll
    for (int i = 0; i < 32; i += 8) {
        int k = k0 + ty + i;
        tile[ty + i][tx] = (k < K) ? W[(size_t)k * N + (n0 + tx)] : 0.f;
    }
    __syncthreads();
    #pragma unroll
    for (int i = 0; i < 32; i += 8) {
        int n = n0 + ty + i, k = k0 + tx;
        WT[(size_t)n * KP + k] = __float2bfloat16(tile[tx][ty + i]);
    }
}

__global__ __launch_bounds__(256) void prep_mini(const float* __restrict__ w0,
                                                 const float* __restrict__ w1,
                                                 const float* __restrict__ dense,
                                                 __hip_bfloat16* __restrict__ W0T,
                                                 __hip_bfloat16* __restrict__ W1T,
                                                 __hip_bfloat16* __restrict__ Xd,
                                                 float* __restrict__ NN) {
    __shared__ float tile[32][33];
    const int b = blockIdx.x, tid = threadIdx.x;
    if (b < 1856) {
        transpose_tile(w0, W0T, 1805, 1024, KP0, (b % 58) * 32, (b / 58) * 32, tile, tid);
    } else if (b < 2368) {
        int bb = b - 1856;
        transpose_tile(w1, W1T, 1024, 512, 1024, (bb % 32) * 32, (bb / 32) * 32, tile, tid);
    } else {
        int r = (b - 2368) * 256 + tid;      // 0..16383
        NN[r] = 0.f;
        float d[16];
        #pragma unroll
        for (int j = 0; j < 16; ++j) d[j] = 0.f;
        #pragma unroll
        for (int j = 0; j < 13; ++j) d[j] = dense[(size_t)r * 13 + j];
        bf16x8* dst = (bf16x8*)(Xd + (size_t)r * 64);
        f32x4 z = {0.f, 0.f, 0.f, 0.f};
        dst[0] = pack8(*(f32x4*)&d[0], *(f32x4*)&d[4]);
        dst[1] = pack8(*(f32x4*)&d[8], *(f32x4*)&d[12]);
        #pragma unroll
        for (int j = 2; j < 8; ++j) dst[j] = pack8(z, z);
    }
}

// ==================== gather-fused GEMM0
// H0 = relu(X @ w0 + b0) where X rows are gathered/computed on the fly.
// BM=128, BN=256, BK=64, grid 512 = 128 br x 4 bc, 512 threads (8 waves, 2Mx4N).
// LDS: 2 x (A 16K + B 32K) = 96K + persistent mh-f26 16K = 112K.
// K-tiles: T=0..25 onehot gather (reg-staged), 26 = mh persistent, 27 = mh regs, 28 = Xd.
struct St {
    char* lds;
    const char* Bg;          // W0T + bc*256 rows
    const char* XdB;         // Xd + br*128 rows
    const float* emb;
    const int* ohp;          // onehot + (br*128 + r0)*26
    const float* fmw;
    f32x4 acc[4][4];
    f32x4 g[2][2][2];        // [parity][chunk][lo/hi]
    float fw[2][2];
    int idxs[2][2];
    f32x4 Se[2][2];
    float Sq[2], fm1[2];
    bf16x8 mh27[2];
    int tid, wv1024, s, r0, swzB;
    int dstA[2];
    int abase, bbase, xr0, xr1;
};

template<int P> __device__ __forceinline__ void issue_g(St& st) {
    #pragma unroll
    for (int c = 0; c < 2; ++c) {
        const float* e = st.emb + (size_t)st.idxs[P][c] * 64 + st.s * 8;
        st.g[P][c][0] = *(const f32x4*)e;
        st.g[P][c][1] = *(const f32x4*)(e + 4);
    }
    st.fw[P][0] = st.fmw[st.idxs[P][0]];
    st.fw[P][1] = st.fmw[st.idxs[P][1]];
}

template<int P> __device__ __forceinline__ void consume_g(St& st, char* Lb) {
    #pragma unroll
    for (int c = 0; c < 2; ++c) {
        f32x4 lo = st.g[P][c][0], hi = st.g[P][c][1];
        st.Se[c][0] += lo; st.Se[c][1] += hi;
        st.Sq[c] += lo[0]*lo[0] + lo[1]*lo[1] + lo[2]*lo[2] + lo[3]*lo[3]
                  + hi[0]*hi[0] + hi[1]*hi[1] + hi[2]*hi[2] + hi[3]*hi[3];
        st.fm1[c] += st.fw[P][c];
        *(bf16x8*)(Lb + st.dstA[c]) = pack8(lo, hi);
    }
}

__device__ __forceinline__ void stB0(St& st, char* Lb, int Tt) {
    #pragma unroll
    for (int i = 0; i < 4; ++i) {
        int gr = i * 64 + st.r0;
        load_lds16(st.Bg + (size_t)gr * (KP0 * 2) + Tt * 128 + st.swzB,
                   Lb + 16384 + i * 8192 + st.wv1024);
    }
}

__device__ __forceinline__ void stA28(St& st, char* Lb) {
    #pragma unroll
    for (int i = 0; i < 2; ++i) {
        int gr = i * 64 + st.r0;
        load_lds16(st.XdB + (size_t)gr * 128 + st.swzB,
                   Lb + i * 8192 + st.wv1024);
    }
}

template<int T> __device__ __forceinline__ void ktile(St& st) {
    char* Lb = st.lds + (T & 1) * 49152;
    const char* Ab = (T == 26) ? (st.lds + 98304) : Lb;
    const char* Bb = Lb + 16384;
    // idx prefetch for tile T+5
    if constexpr (T >= 1 && T <= 20) {
        st.idxs[(T + 1) & 1][0] = st.ohp[T + 5];
        st.idxs[(T + 1) & 1][1] = st.ohp[64 * 26 + T + 5];
    }
    bf16x8 a[4], b[4];
    // ---- ph1: kk0
    #pragma unroll
    for (int m = 0; m < 4; ++m) a[m] = *(const bf16x8*)(Ab + st.abase + m * 2048 + st.xr0);
    #pragma unroll
    for (int n = 0; n < 4; ++n) b[n] = *(const bf16x8*)(Bb + st.bbase + n * 2048 + st.xr0);
    __builtin_amdgcn_s_setprio(1);
    #pragma unroll
    for (int m = 0; m < 4; ++m)
        #pragma unroll
        for (int n = 0; n < 4; ++n)
            st.acc[m][n] = __builtin_amdgcn_mfma_f32_16x16x32_bf16(a[m], b[n], st.acc[m][n], 0, 0, 0);
    __builtin_amdgcn_s_setprio(0);
    // ---- ph2: kk1
    #pragma unroll
    for (int m = 0; m < 4; ++m) a[m] = *(const bf16x8*)(Ab + st.abase + m * 2048 + st.xr1);
    #pragma unroll
    for (int n = 0; n < 4; ++n) b[n] = *(const bf16x8*)(Bb + st.bbase + n * 2048 + st.xr1);
    __builtin_amdgcn_s_setprio(1);
    #pragma unroll
    for (int m = 0; m < 4; ++m)
        #pragma unroll
        for (int n = 0; n < 4; ++n)
            st.acc[m][n] = __builtin_amdgcn_mfma_f32_16x16x32_bf16(a[m], b[n], st.acc[m][n], 0, 0, 0);
    __builtin_amdgcn_s_setprio(0);
    if constexpr (T == 28) return;
    // ---- tail: all reads of current buffer done after this barrier
    SBAR0();
    __builtin_amdgcn_s_barrier();
    constexpr int V1 = (T==0)?6 : (T==1)?12 : (T<=20)?14 : (T==21)?12 : (T==22)?10 : (T==23)?4 : -1;
    constexpr int V2 = (T>=2 && T<=20)?16 : (T==21)?14 : -1;
    constexpr int V3 = (T==0)?-1 : (T<=20)?18 : (T==21)?16 : (T==22)?10 : (T<=25)?4 : (T==26)?6 : 0;
    if constexpr (T <= 23) { vmw<(V1 < 0 ? 0 : V1)>(); consume_g<(T & 1)>(st, Lb); }
    if constexpr (T == 25) {
        *(bf16x8*)(Lb + st.dstA[0]) = st.mh27[0];
        *(bf16x8*)(Lb + st.dstA[1]) = st.mh27[1];
    }
    if constexpr (T <= 26) stB0(st, Lb, T + 2);
    if constexpr (T == 26) stA28(st, Lb);
    if constexpr (T <= 21) {
        if constexpr (T >= 2) vmw<(V2 < 0 ? 0 : V2)>();
        issue_g<(T & 1)>(st);
    }
    if constexpr (V3 >= 0) vmw<(V3 < 0 ? 0 : V3)>();
    LGKM0();
    SBAR0();
    __builtin_amdgcn_s_barrier();
}

__global__ __launch_bounds__(512, 2) void gemm0_fused(const int* __restrict__ onehot,
                                                      const int* __restrict__ multihot,
                                                      const float* __restrict__ fm_w,
                                                      const float* __restrict__ fm_emb,
                                                      const __hip_bfloat16* __restrict__ W0T,
                                                      const __hip_bfloat16* __restrict__ Xd,
                                                      const float* __restrict__ b0,
                                                      __hip_bfloat16* __restrict__ H0,
                                                      float* __restrict__ FM) {
    __shared__ __align__(16) char lds[114688];   // 2x48K buffers + 16K mh-f26
    const int tid = threadIdx.x;
    const int wv = tid >> 6, lane = tid & 63;
    const int lr = lane & 15, lg = lane >> 4;
    const int wr = wv >> 2, wc = wv & 3;

    // sibling quads (same br, bc 0..3) share an XCD for L2 gather reuse
    const int bid = blockIdx.x;
    const int x = bid & 7, j = bid >> 3;
    const int br = x * 16 + (j >> 2), bc = j & 3;

    St st;
    st.lds = lds;
    st.Bg  = (const char*)(W0T + (size_t)(bc * 256) * KP0);
    st.XdB = (const char*)(Xd + (size_t)(br * 128) * 64);
    st.emb = fm_emb;
    st.fmw = fm_w;
    st.tid = tid; st.wv1024 = wv * 1024;
    st.s = tid & 7; st.r0 = tid >> 3;
    st.ohp = onehot + (size_t)(br * 128 + st.r0) * 26;
    st.swzB = ((st.s) ^ (st.r0 & 7)) * 16;
    st.dstA[0] = st.r0 * 128 + st.swzB;
    st.dstA[1] = 8192 + st.r0 * 128 + st.swzB;
    st.abase = (wr * 64 + lr) * 128;
    st.bbase = (wc * 64 + lr) * 128;
    st.xr0 = ((lg) ^ (lr & 7)) * 16;
    st.xr1 = ((lg + 4) ^ (lr & 7)) * 16;
    #pragma unroll
    for (int m = 0; m < 4; ++m)
        #pragma unroll
        for (int n = 0; n < 4; ++n) st.acc[m][n] = f32x4{0.f, 0.f, 0.f, 0.f};
    #pragma unroll
    for (int c = 0; c < 2; ++c) {
        st.Se[c][0] = f32x4{0.f,0.f,0.f,0.f}; st.Se[c][1] = f32x4{0.f,0.f,0.f,0.f};
        st.Sq[c] = 0.f; st.fm1[c] = 0.f;
    }

    // ---- prologue A: multihot means (fields 26,27) -> persistent LDS / regs + FM accum
    #pragma unroll
    for (int rf = 0; rf < 4; ++rf) {
        const int c = rf >> 1, f = rf & 1;
        const int row = c * 64 + st.r0;
        const int* mp = multihot + (size_t)(br * 128 + row) * 40 + f * 20;
        int q[20];
        *(int4*)&q[0]  = *(const int4*)(mp);
        *(int4*)&q[4]  = *(const int4*)(mp + 4);
        *(int4*)&q[8]  = *(const int4*)(mp + 8);
        *(int4*)&q[12] = *(const int4*)(mp + 12);
        *(int4*)&q[16] = *(const int4*)(mp + 16);
        f32x4 lo = {0.f,0.f,0.f,0.f}, hi = {0.f,0.f,0.f,0.f};
        #pragma unroll
        for (int l = 0; l < 20; ++l) {
            const float* e = fm_emb + (size_t)q[l] * 64 + st.s * 8;
            lo += *(const f32x4*)e;
            hi += *(const f32x4*)(e + 4);
        }
        lo *= 0.05f; hi *= 0.05f;
        st.Se[c][0] += lo; st.Se[c][1] += hi;
        st.Sq[c] += lo[0]*lo[0] + lo[1]*lo[1] + lo[2]*lo[2] + lo[3]*lo[3]
                  + hi[0]*hi[0] + hi[1]*hi[1] + hi[2]*hi[2] + hi[3]*hi[3];
        bf16x8 pk = pack8(lo, hi);
        if (f == 0) *(bf16x8*)(lds + 98304 + st.dstA[c]) = pk;
        else        st.mh27[c] = pk;
    }

    // ---- prologue B: stage tiles 0,1; put g(2),g(3) + idx(4),idx(5) in flight
    int i0[6], i1[6];
    #pragma unroll
    for (int t = 0; t < 6; ++t) { i0[t] = st.ohp[t]; i1[t] = st.ohp[64 * 26 + t]; }
    st.idxs[0][0] = i0[0]; st.idxs[0][1] = i1[0]; issue_g<0>(st);
    st.idxs[1][0] = i0[1]; st.idxs[1][1] = i1[1]; issue_g<1>(st);
    stB0(st, lds, 0);
    stB0(st, lds + 49152, 1);
    vmw<14>(); consume_g<0>(st, lds);            // A(0) -> buf0
    vmw<8>();  consume_g<1>(st, lds + 49152);    // A(1) -> buf1
    st.idxs[0][0] = i0[2]; st.idxs[0][1] = i1[2]; issue_g<0>(st);   // g(2)
    st.idxs[1][0] = i0[3]; st.idxs[1][1] = i1[3]; issue_g<1>(st);   // g(3)
    st.idxs[0][0] = i0[4]; st.idxs[0][1] = i1[4];
    st.idxs[1][0] = i0[5]; st.idxs[1][1] = i1[5];
    vmw<12>();                                    // drain B(0),B(1); keep g(2),g(3)
    LGKM0();
    SBAR0();
    __builtin_amdgcn_s_barrier();

    // ---- 29 K-tiles
    #define KT(T) ktile<T>(st)
    KT(0);  KT(1);  KT(2);  KT(3);  KT(4);  KT(5);  KT(6);  KT(7);  KT(8);  KT(9);
    KT(10); KT(11); KT(12); KT(13); KT(14); KT(15); KT(16); KT(17); KT(18); KT(19);
    KT(20); KT(21); KT(22); KT(23); KT(24); KT(25); KT(26); KT(27); KT(28);
    #undef KT

    // ---- epilogue: H0 = relu(acc + b0); FM from bc0 blocks
    const float bv = b0[0];
    const int rowb = br * 128 + wr * 64, colb = bc * 256 + wc * 64;
    #pragma unroll
    for (int m = 0; m < 4; ++m)
        #pragma unroll
        for (int n = 0; n < 4; ++n)
            #pragma unroll
            for (int r = 0; r < 4; ++r) {
                int row = rowb + m * 16 + lg * 4 + r;
                int col = colb + n * 16 + lr;
                H0[(size_t)row * 1024 + col] = __float2bfloat16(fmaxf(st.acc[m][n][r] + bv, 0.f));
            }
    if (bc == 0) {
        #pragma unroll
        for (int c = 0; c < 2; ++c) {
            f32x4 s0 = st.Se[c][0], s1 = st.Se[c][1];
            float s2 = s0[0]*s0[0] + s0[1]*s0[1] + s0[2]*s0[2] + s0[3]*s0[3]
                     + s1[0]*s1[0] + s1[1]*s1[1] + s1[2]*s1[2] + s1[3]*s1[3];
            float part = 0.5f * (s2 - st.Sq[c]);
            part += __shfl_xor(part, 1);
            part += __shfl_xor(part, 2);
            part += __shfl_xor(part, 4);
            if (st.s == 0) FM[br * 128 + c * 64 + st.r0] = part + st.fm1[c];
        }
    }
}

// ==================== GEMM1 (phase-interleaved, fused w2 dot) — unchanged from R6
template<int NREP, bool FUSED>
__global__ __launch_bounds__(512, 2) void gemm_pipe(const __hip_bfloat16* __restrict__ A,
                                                    const __hip_bfloat16* __restrict__ BT,
                                                    const float* __restrict__ bias,
                                                    __hip_bfloat16* __restrict__ C,
                                                    const float* __restrict__ w2,
                                                    float* __restrict__ NN,
                                                    int M, int N, int K) {
    constexpr int BUFB = 32768 + NREP * 8192;
    constexpr int NBC  = NREP;
    __shared__ __align__(16) char lds[2][BUFB];

    const int tid = threadIdx.x;
    const int wv = tid >> 6, lane = tid & 63;
    const int lr = lane & 15, lg = lane >> 4;
    const int wr = wv >> 2, wc = wv & 3;

    const int bid = blockIdx.x;
    const int wg = (bid & 7) * 32 + (bid >> 3);
    const int br = wg >> 2, bc = wg & 3;

    const size_t rowBytes = (size_t)K * 2;
    const char* Ab = (const char*)A + (size_t)(br * 256) * rowBytes;
    const char* Bb = (const char*)BT + (size_t)(bc * (NREP * 64)) * rowBytes;
    const int nt = K >> 6;

    const int srcx = ((tid & 7) ^ ((tid >> 3) & 7)) << 4;
    auto stA = [&](int tt, int c) {
        int gr = c * 64 + (tid >> 3);
        load_lds16(Ab + (size_t)gr * rowBytes + (size_t)tt * 128 + srcx,
                   &lds[tt & 1][c * 8192 + wv * 1024]);
    };
    auto stB = [&](int tt, int c) {
        int gr = c * 64 + (tid >> 3);
        load_lds16(Bb + (size_t)gr * rowBytes + (size_t)tt * 128 + srcx,
                   &lds[tt & 1][32768 + c * 8192 + wv * 1024]);
    };

    f32x4 acc[8][NREP] = {};

    #pragma unroll
    for (int c = 0; c < 4; ++c) stA(0, c);
    #pragma unroll
    for (int c = 0; c < NBC; ++c) stB(0, c);
    #pragma unroll
    for (int c = 0; c < 4; ++c) stA(1, c);
    VMCNT(4);
    SBAR0();
    __builtin_amdgcn_s_barrier();

    const int xr0 = (lg ^ (lr & 7)) << 4;
    const int xr1 = ((4 + lg) ^ (lr & 7)) << 4;
    const int arow = (wr * 128 + lr) * 128;
    const int brow = 32768 + (wc * (NREP * 16) + lr) * 128;

    for (int t = 0; t < nt; ++t) {
        const char* L = &lds[t & 1][0];
        const bool sB = (t + 1 < nt), sA = (t + 2 < nt);
        bf16x8 a[4][2], a2[4][2], b01[2][2], b23[2][2];

        #pragma unroll
        for (int m = 0; m < 4; ++m) {
            a[m][0] = *(const bf16x8*)(L + arow + m * 2048 + xr0);
            a[m][1] = *(const bf16x8*)(L + arow + m * 2048 + xr1);
        }
        {
            constexpr int NLO = (NREP == 4) ? 2 : 1;
            #pragma unroll
            for (int n = 0; n < NLO; ++n) {
                b01[n][0] = *(const bf16x8*)(L + brow + n * 2048 + xr0);
                b01[n][1] = *(const bf16x8*)(L + brow + n * 2048 + xr1);
            }
        }
        if (sB) { stB(t + 1, 0); if constexpr (NREP == 4) stB(t + 1, 1); }
        SBAR0();
        __builtin_amdgcn_s_barrier();
        LGKM0();
        __builtin_amdgcn_s_setprio(1);
        #pragma unroll
        for (int m = 0; m < 4; ++m)
            #pragma unroll
            for (int n = 0; n < ((NREP == 4) ? 2 : 1); ++n)
                #pragma unroll
                for (int kk = 0; kk < 2; ++kk)
                    acc[m][n] = __builtin_amdgcn_mfma_f32_16x16x32_bf16(a[m][kk], b01[n][kk], acc[m][n], 0, 0, 0);
        __builtin_amdgcn_s_setprio(0);
        SBAR0();
        __builtin_amdgcn_s_barrier();

        #pragma unroll
        for (int m = 0; m < 4; ++m) {
            a2[m][0] = *(const bf16x8*)(L + arow + (4 + m) * 2048 + xr0);
            a2[m][1] = *(const bf16x8*)(L + arow + (4 + m) * 2048 + xr1);
        }
        if (sB) { if constexpr (NREP == 4) { stB(t + 1, 2); stB(t + 1, 3); } else stB(t + 1, 1); }
        SBAR0();
        __builtin_amdgcn_s_barrier();
        LGKM0();
        __builtin_amdgcn_s_setprio(1);
        #pragma unroll
        for (int m = 0; m < 4; ++m)
            #pragma unroll
            for (int n = 0; n < ((NREP == 4) ? 2 : 1); ++n)
                #pragma unroll
                for (int kk = 0; kk < 2; ++kk)
                    acc[4 + m][n] = __builtin_amdgcn_mfma_f32_16x16x32_bf16(a2[m][kk], b01[n][kk], acc[4 + m][n], 0, 0, 0);
        __builtin_amdgcn_s_setprio(0);
        SBAR0();
        __builtin_amdgcn_s_barrier();

        {
            constexpr int NHI = (NREP == 4) ? 2 : 1;
            constexpr int NO  = (NREP == 4) ? 2 : 1;
            #pragma unroll
            for (int n = 0; n < NHI; ++n) {
                b23[n][0] = *(const bf16x8*)(L + brow + (NO + n) * 2048 + xr0);
                b23[n][1] = *(const bf16x8*)(L + brow + (NO + n) * 2048 + xr1);
            }
        }
        if (sA) { stA(t + 2, 0); stA(t + 2, 1); }
        SBAR0();
        __builtin_amdgcn_s_barrier();
        LGKM0();
        __builtin_amdgcn_s_setprio(1);
        #pragma unroll
        for (int m = 0; m < 4; ++m)
            #pragma unroll
            for (int n = 0; n < ((NREP == 4) ? 2 : 1); ++n)
                #pragma unroll
                for (int kk = 0; kk < 2; ++kk)
                    acc[m][((NREP == 4) ? 2 : 1) + n] = __builtin_amdgcn_mfma_f32_16x16x32_bf16(a[m][kk], b23[n][kk], acc[m][((NREP == 4) ? 2 : 1) + n], 0, 0, 0);
        __builtin_amdgcn_s_setprio(0);
        SBAR0();
        __builtin_amdgcn_s_barrier();

        if (sA) { stA(t + 2, 2); stA(t + 2, 3); }
        SBAR0();
        __builtin_amdgcn_s_barrier();
        LGKM0();
        __builtin_amdgcn_s_setprio(1);
        #pragma unroll
        for (int m = 0; m < 4; ++m)
            #pragma unroll
            for (int n = 0; n < ((NREP == 4) ? 2 : 1); ++n)
                #pragma unroll
                for (int kk = 0; kk < 2; ++kk)
                    acc[4 + m][((NREP == 4) ? 2 : 1) + n] = __builtin_amdgcn_mfma_f32_16x16x32_bf16(a2[m][kk], b23[n][kk], acc[4 + m][((NREP == 4) ? 2 : 1) + n], 0, 0, 0);
        __builtin_amdgcn_s_setprio(0);
        SBAR0();
        if (sA)      VMCNT(4);
        else if (sB) VMCNT(0);
        if (sB) __builtin_amdgcn_s_barrier();
    }

    const float bv = bias[0];
    const int rowb = br * 256 + wr * 128, colb = bc * (NREP * 64) + wc * (NREP * 16);
    if constexpr (FUSED) {
        float w2v[NREP];
        #pragma unroll
        for (int n = 0; n < NREP; ++n) w2v[n] = w2[colb + n * 16 + lr];
        #pragma unroll
        for (int m = 0; m < 8; ++m)
            #pragma unroll
            for (int r = 0; r < 4; ++r) {
                float p = 0.f;
                #pragma unroll
                for (int n = 0; n < NREP; ++n)
                    p += fmaxf(acc[m][n][r] + bv, 0.f) * w2v[n];
                #pragma unroll
                for (int off = 8; off; off >>= 1) p += __shfl_xor(p, off);
                if (lr == 0)
                    atomicAdd(&NN[rowb + m * 16 + lg * 4 + r], p);
            }
    } else {
        #pragma unroll
        for (int m = 0; m < 8; ++m)
            #pragma unroll
            for (int n = 0; n < NREP; ++n)
                #pragma unroll
                for (int r = 0; r < 4; ++r) {
                    int row = rowb + m * 16 + lg * 4 + r;
                    int col = colb + n * 16 + lr;
                    C[(size_t)row * N + col] = __float2bfloat16(fmaxf(acc[m][n][r] + bv, 0.f));
                }
    }
}

// ==================== finish: out = sigmoid(FM + relu(NN + b2))
__global__ __launch_bounds__(256) void finish_k(const float* __restrict__ NN,
                                                const float* __restrict__ b2,
                                                const float* __restrict__ FM,
                                                float* __restrict__ out) {
    const int row = blockIdx.x * 256 + threadIdx.x;
    float v = fmaxf(NN[row] + b2[0], 0.f) + FM[row];
    out[row] = 1.f / (1.f + expf(-v));
}

extern "C" void kernel_launch(void* const* d_in, const int* in_sizes, int n_in,
                              void* d_out, int out_size, void* d_ws, size_t ws_size,
                              hipStream_t stream) {
    const float* dense    = (const float*)d_in[0];
    const int*   onehot   = (const int*)d_in[1];
    const int*   multihot = (const int*)d_in[2];
    const float* fm_w     = (const float*)d_in[3];
    const float* fm_emb   = (const float*)d_in[4];
    const float* w0       = (const float*)d_in[5];
    const float* b0       = (const float*)d_in[6];
    const float* w1       = (const float*)d_in[7];
    const float* b1       = (const float*)d_in[8];
    const float* w2       = (const float*)d_in[9];
    const float* b2       = (const float*)d_in[10];
    float* out = (float*)d_out;

    char* ws = (char*)d_ws;
    __hip_bfloat16* H0  = (__hip_bfloat16*)(ws + OFF_H0);
    __hip_bfloat16* W0T = (__hip_bfloat16*)(ws + OFF_W0T);
    __hip_bfloat16* W1T = (__hip_bfloat16*)(ws + OFF_W1T);
    float*          FM  = (float*)(ws + OFF_FM);
    float*          NN  = (float*)(ws + OFF_NN);
    __hip_bfloat16* Xd  = (__hip_bfloat16*)(ws + OFF_XD);

    prep_mini<<<2432, 256, 0, stream>>>(w0, w1, dense, W0T, W1T, Xd, NN);
    gemm0_fused<<<512, 512, 0, stream>>>(onehot, multihot, fm_w, fm_emb, W0T, Xd, b0, H0, FM);
    gemm_pipe<2, true><<<256, 512, 0, stream>>>(H0, W1T, b1, nullptr, w2, NN, NB, 512, 1024);
    finish_k<<<64, 256, 0, stream>>>(NN, b2, FM, out);
}

// Round 8
// 165.328 us; speedup vs baseline: 2.5769x; 2.5769x over previous
//
#include <hip/hip_runtime.h>
#include <hip/hip_bf16.h>
#include <math.h>

typedef __attribute__((ext_vector_type(8))) short bf16x8;
typedef __attribute__((ext_vector_type(4))) float f32x4;

typedef void __attribute__((address_space(1))) gvoid_t;
typedef void __attribute__((address_space(3))) lvoid_t;

#define KP0   1856          // NN_IN (1805) padded to multiple of 64
#define NB    16384
// workspace layout (bytes)
#define OFF_X    0u
#define OFF_H0   60817408u  // 16384*1856*2
#define OFF_W0T  94371840u  // +16384*1024*2
#define OFF_W1T  98172928u  // +1856*1024*2
#define OFF_FM   99221504u  // +512*1024*2
#define OFF_NN   99287040u  // +16384*4

#define VMCNT(n) asm volatile("s_waitcnt vmcnt(" #n ")" ::: "memory")
#define SBAR0()  __builtin_amdgcn_sched_barrier(0)

__device__ __forceinline__ float bf2f(short s) {
    return __uint_as_float(((unsigned)(unsigned short)s) << 16);
}

__device__ __forceinline__ void load_lds16(const void* g, void* l) {
    __builtin_amdgcn_global_load_lds(
        (gvoid_t*)(uintptr_t)g,
        (lvoid_t*)(unsigned)(uintptr_t)l,
        16, 0, 0);
}

// ---------------- merged prep: gather+FM+zero-NN (blocks 0..4095), w0 transpose
//                  (next 1856), w1 transpose (next 512). 256 threads/block.
__device__ __forceinline__ void transpose_tile(const float* __restrict__ W,
                                               __hip_bfloat16* __restrict__ WT,
                                               int K, int N, int KP, int k0, int n0,
                                               float (*tile)[33], int tid) {
    const int tx = tid & 31, ty = tid >> 5;
    #pragma unroll
    for (int i = 0; i < 32; i += 8) {
        int k = k0 + ty + i;
        tile[ty + i][tx] = (k < K) ? W[(size_t)k * N + (n0 + tx)] : 0.f;
    }
    __syncthreads();
    #pragma unroll
    for (int i = 0; i < 32; i += 8) {
        int n = n0 + ty + i, k = k0 + tx;
        WT[(size_t)n * KP + k] = __float2bfloat16(tile[tx][ty + i]);
    }
}

__global__ __launch_bounds__(256) void prep(const float* __restrict__ dense,
                                            const int* __restrict__ onehot,
                                            const int* __restrict__ multihot,
                                            const float* __restrict__ fm_w,
                                            const float* __restrict__ fm_emb,
                                            const float* __restrict__ w0,
                                            const float* __restrict__ w1,
                                            __hip_bfloat16* __restrict__ X,
                                            float* __restrict__ FM,
                                            float* __restrict__ NN,
                                            __hip_bfloat16* __restrict__ W0T,
                                            __hip_bfloat16* __restrict__ W1T) {
    __shared__ float tile[32][33];
    const int b = blockIdx.x, tid = threadIdx.x;
    if (b >= 4096) {
        if (b < 4096 + 1856) {
            int bb = b - 4096;
            transpose_tile(w0, W0T, 1805, 1024, KP0, (bb % 58) * 32, (bb / 58) * 32, tile, tid);
        } else {
            int bb = b - 5952;
            transpose_tile(w1, W1T, 1024, 512, 1024, (bb % 32) * 32, (bb / 32) * 32, tile, tid);
        }
        return;
    }
    const int wv = tid >> 6, lane = tid & 63;
    const int row = b * 4 + wv;
    const int oh = (lane < 26) ? onehot[row * 26 + lane] : 0;
    const int mh = (lane < 40) ? multihot[row * 40 + lane] : 0;
    const float fm1 = (lane < 26) ? fm_w[oh] : 0.f;
    __hip_bfloat16* Xr = X + (size_t)row * KP0;
    float s = 0.f, sq = 0.f;
    for (int f = 0; f < 26; ++f) {
        int idx = __shfl(oh, f);
        float v = fm_emb[(size_t)idx * 64 + lane];
        s += v; sq += v * v;
        Xr[f * 64 + lane] = __float2bfloat16(v);
    }
    #pragma unroll
    for (int h = 0; h < 2; ++h) {
        float a = 0.f;
        for (int l = 0; l < 20; ++l) {
            int idx = __shfl(mh, h * 20 + l);
            a += fm_emb[(size_t)idx * 64 + lane];
        }
        float v = a * (1.f / 20.f);
        s += v; sq += v * v;
        Xr[(26 + h) * 64 + lane] = __float2bfloat16(v);
    }
    float red = 0.5f * (s * s - sq) + fm1;
    #pragma unroll
    for (int off = 32; off; off >>= 1) red += __shfl_xor(red, off);
    if (lane == 0) FM[row] = red;
    if (lane == 32) NN[row] = 0.f;
    float dv = (lane < 13) ? dense[row * 13 + lane] : 0.f;
    Xr[1792 + lane] = __float2bfloat16(dv);   // rows 1792..1855: dense + zero pad
}

// ---------------- single-barrier double-buffered GEMM
// C(MxN,bf16) = relu(A(MxK)*BT(NxK)^T + bias). BM=256, BN=NREP*64, BK=64.
// 8 waves (2M x 4N), wave tile 128 x NREP*16. Regions: A[2] 32KB, B[2] NREP*8KB.
// Stage tile t+1 (other buffer) at tile top; ONE vmcnt(0)+barrier per tile at
// bottom (loads get the whole tile ~2800cyc >> 900cyc HBM latency to land).
// No intra-tile barriers: reads of buf[t&1] never collide with writes to
// buf[(t+1)&1]; overwrite of buf[t&1] happens in tile t+1 after the barrier.
// LDS rows 128B, 16B-slot XOR swizzle (slot ^= row&7) both-sides (conflict-free).
// FUSED: accumulate relu(C+bias)*w2[col] into NN[row] (atomic) instead of storing C.
// Requires: M%256==0, grid=(M/256)*(N/BN) with N/BN==4, K%64==0, K/64>=2.
template<int NREP, bool FUSED>
__global__ __launch_bounds__(512, 2) void gemm_db(const __hip_bfloat16* __restrict__ A,
                                                  const __hip_bfloat16* __restrict__ BT,
                                                  const float* __restrict__ bias,
                                                  __hip_bfloat16* __restrict__ C,
                                                  const float* __restrict__ w2,
                                                  float* __restrict__ NN,
                                                  int M, int N, int K) {
    constexpr int BREG = NREP * 8192;              // one B region
    constexpr int NLO  = (NREP == 4) ? 2 : 1;
    __shared__ __align__(16) char lds[65536 + 2 * BREG];   // A[2]:64KB + B[2]

    const int tid = threadIdx.x;
    const int wv = tid >> 6, lane = tid & 63;
    const int lr = lane & 15, lg = lane >> 4;
    const int wr = wv >> 2, wc = wv & 3;

    const int bid = blockIdx.x;                    // XCD-chunked swizzle, grid == 256
    const int wg = (bid & 7) * 32 + (bid >> 3);
    const int br = wg >> 2, bc = wg & 3;

    const size_t rowBytes = (size_t)K * 2;
    const char* Ab = (const char*)A + (size_t)(br * 256) * rowBytes;
    const char* Bb = (const char*)BT + (size_t)(bc * (NREP * 64)) * rowBytes;
    const int nt = K >> 6;

    const int srcx = ((tid & 7) ^ ((tid >> 3) & 7)) << 4;   // source-side slot swizzle
    auto stA = [&](int tt, int c) {
        int gr = c * 64 + (tid >> 3);
        load_lds16(Ab + (size_t)gr * rowBytes + (size_t)tt * 128 + srcx,
                   &lds[(tt & 1) * 32768 + c * 8192 + wv * 1024]);
    };
    auto stB = [&](int tt, int c) {
        int gr = c * 64 + (tid >> 3);
        load_lds16(Bb + (size_t)gr * rowBytes + (size_t)tt * 128 + srcx,
                   &lds[65536 + (tt & 1) * BREG + c * 8192 + wv * 1024]);
    };

    f32x4 acc[8][NREP] = {};

    // prologue: stage tile 0, drain, barrier
    #pragma unroll
    for (int c = 0; c < 4; ++c) stA(0, c);
    #pragma unroll
    for (int c = 0; c < NREP; ++c) stB(0, c);
    VMCNT(0);
    SBAR0();
    __builtin_amdgcn_s_barrier();

    const int xr0 = (lg ^ (lr & 7)) << 4;          // read-side slot swizzle, kk=0
    const int xr1 = ((4 + lg) ^ (lr & 7)) << 4;    // kk=1
    const int arow = (wr * 128 + lr) * 128;
    const int brow = (wc * (NREP * 16) + lr) * 128;

    for (int t = 0; t < nt; ++t) {
        // ---- stage t+1 at tile top (full tile of latency to land)
        if (t + 1 < nt) {
            #pragma unroll
            for (int c = 0; c < 4; ++c) stA(t + 1, c);
            #pragma unroll
            for (int c = 0; c < NREP; ++c) stB(t + 1, c);
        }
        SBAR0();   // pin load issues before the read/MFMA body

        const char* LA = &lds[(t & 1) * 32768];
        const char* LB = &lds[65536 + (t & 1) * BREG];
        bf16x8 a1[4][2], a2[4][2], bl[NLO][2], bh[NLO][2];

        // ---- chunk 1: a0-3 + b-lo; MFMA m0-3 x n-lo
        #pragma unroll
        for (int m = 0; m < 4; ++m) {
            a1[m][0] = *(const bf16x8*)(LA + arow + m * 2048 + xr0);
            a1[m][1] = *(const bf16x8*)(LA + arow + m * 2048 + xr1);
        }
        #pragma unroll
        for (int n = 0; n < NLO; ++n) {
            bl[n][0] = *(const bf16x8*)(LB + brow + n * 2048 + xr0);
            bl[n][1] = *(const bf16x8*)(LB + brow + n * 2048 + xr1);
        }
        __builtin_amdgcn_s_setprio(1);
        #pragma unroll
        for (int m = 0; m < 4; ++m)
            #pragma unroll
            for (int n = 0; n < NLO; ++n)
                #pragma unroll
                for (int kk = 0; kk < 2; ++kk)
                    acc[m][n] = __builtin_amdgcn_mfma_f32_16x16x32_bf16(a1[m][kk], bl[n][kk], acc[m][n], 0, 0, 0);
        __builtin_amdgcn_s_setprio(0);

        // ---- chunk 2: a4-7; MFMA m4-7 x n-lo
        #pragma unroll
        for (int m = 0; m < 4; ++m) {
            a2[m][0] = *(const bf16x8*)(LA + arow + (4 + m) * 2048 + xr0);
            a2[m][1] = *(const bf16x8*)(LA + arow + (4 + m) * 2048 + xr1);
        }
        __builtin_amdgcn_s_setprio(1);
        #pragma unroll
        for (int m = 0; m < 4; ++m)
            #pragma unroll
            for (int n = 0; n < NLO; ++n)
                #pragma unroll
                for (int kk = 0; kk < 2; ++kk)
                    acc[4 + m][n] = __builtin_amdgcn_mfma_f32_16x16x32_bf16(a2[m][kk], bl[n][kk], acc[4 + m][n], 0, 0, 0);
        __builtin_amdgcn_s_setprio(0);

        // ---- chunk 3: b-hi; MFMA m0-3 x n-hi
        #pragma unroll
        for (int n = 0; n < NLO; ++n) {
            bh[n][0] = *(const bf16x8*)(LB + brow + (NLO + n) * 2048 + xr0);
            bh[n][1] = *(const bf16x8*)(LB + brow + (NLO + n) * 2048 + xr1);
        }
        __builtin_amdgcn_s_setprio(1);
        #pragma unroll
        for (int m = 0; m < 4; ++m)
            #pragma unroll
            for (int n = 0; n < NLO; ++n)
                #pragma unroll
                for (int kk = 0; kk < 2; ++kk)
                    acc[m][NLO + n] = __builtin_amdgcn_mfma_f32_16x16x32_bf16(a1[m][kk], bh[n][kk], acc[m][NLO + n], 0, 0, 0);
        __builtin_amdgcn_s_setprio(0);

        // ---- chunk 4: MFMA m4-7 x n-hi
        __builtin_amdgcn_s_setprio(1);
        #pragma unroll
        for (int m = 0; m < 4; ++m)
            #pragma unroll
            for (int n = 0; n < NLO; ++n)
                #pragma unroll
                for (int kk = 0; kk < 2; ++kk)
                    acc[4 + m][NLO + n] = __builtin_amdgcn_mfma_f32_16x16x32_bf16(a2[m][kk], bh[n][kk], acc[4 + m][NLO + n], 0, 0, 0);
        __builtin_amdgcn_s_setprio(0);

        // ---- tile end: wait stage(t+1) landed, sync
        SBAR0();
        if (t + 1 < nt) {
            VMCNT(0);
            __builtin_amdgcn_s_barrier();
        }
    }

    const float bv = bias[0];
    const int rowb = br * 256 + wr * 128, colb = bc * (NREP * 64) + wc * (NREP * 16);
    if constexpr (FUSED) {
        float w2v[NREP];
        #pragma unroll
        for (int n = 0; n < NREP; ++n) w2v[n] = w2[colb + n * 16 + lr];
        #pragma unroll
        for (int m = 0; m < 8; ++m)
            #pragma unroll
            for (int r = 0; r < 4; ++r) {
                float p = 0.f;
                #pragma unroll
                for (int n = 0; n < NREP; ++n)
                    p += fmaxf(acc[m][n][r] + bv, 0.f) * w2v[n];
                #pragma unroll
                for (int off = 8; off; off >>= 1) p += __shfl_xor(p, off);
                if (lr == 0)
                    atomicAdd(&NN[rowb + m * 16 + lg * 4 + r], p);
            }
    } else {
        #pragma unroll
        for (int m = 0; m < 8; ++m)
            #pragma unroll
            for (int n = 0; n < NREP; ++n)
                #pragma unroll
                for (int r = 0; r < 4; ++r) {
                    int row = rowb + m * 16 + lg * 4 + r;
                    int col = colb + n * 16 + lr;
                    C[(size_t)row * N + col] = __float2bfloat16(fmaxf(acc[m][n][r] + bv, 0.f));
                }
    }
}

// ---------------- finish: out = sigmoid(FM + relu(NN + b2))
__global__ __launch_bounds__(256) void finish_k(const float* __restrict__ NN,
                                                const float* __restrict__ b2,
                                                const float* __restrict__ FM,
                                                float* __restrict__ out) {
    const int row = blockIdx.x * 256 + threadIdx.x;
    float v = fmaxf(NN[row] + b2[0], 0.f) + FM[row];
    out[row] = 1.f / (1.f + expf(-v));
}

extern "C" void kernel_launch(void* const* d_in, const int* in_sizes, int n_in,
                              void* d_out, int out_size, void* d_ws, size_t ws_size,
                              hipStream_t stream) {
    const float* dense    = (const float*)d_in[0];
    const int*   onehot   = (const int*)d_in[1];
    const int*   multihot = (const int*)d_in[2];
    const float* fm_w     = (const float*)d_in[3];
    const float* fm_emb   = (const float*)d_in[4];
    const float* w0       = (const float*)d_in[5];
    const float* b0       = (const float*)d_in[6];
    const float* w1       = (const float*)d_in[7];
    const float* b1       = (const float*)d_in[8];
    const float* w2       = (const float*)d_in[9];
    const float* b2       = (const float*)d_in[10];
    float* out = (float*)d_out;

    char* ws = (char*)d_ws;
    __hip_bfloat16* X   = (__hip_bfloat16*)(ws + OFF_X);
    __hip_bfloat16* H0  = (__hip_bfloat16*)(ws + OFF_H0);
    __hip_bfloat16* W0T = (__hip_bfloat16*)(ws + OFF_W0T);
    __hip_bfloat16* W1T = (__hip_bfloat16*)(ws + OFF_W1T);
    float*          FM  = (float*)(ws + OFF_FM);
    float*          NN  = (float*)(ws + OFF_NN);

    prep<<<6464, 256, 0, stream>>>(dense, onehot, multihot, fm_w, fm_emb, w0, w1,
                                   X, FM, NN, W0T, W1T);
    gemm_db<4, false><<<256, 512, 0, stream>>>(X,  W0T, b0, H0, nullptr, nullptr,
                                               NB, 1024, KP0);   // 64x4, 256x256
    gemm_db<2, true><<<256, 512, 0, stream>>>(H0, W1T, b1, nullptr, w2, NN,
                                              NB, 512, 1024);    // 64x4, 256x128, fused dot
    finish_k<<<64, 256, 0, stream>>>(NN, b2, FM, out);
}